// Round 1
// baseline (117.593 us; speedup 1.0000x reference)
//
#include <hip/hip_runtime.h>

typedef unsigned short u16;
typedef unsigned int u32;
typedef _Float16 half8 __attribute__((ext_vector_type(8)));   // MFMA A/B frag
typedef __attribute__((ext_vector_type(4))) float floatx4;    // MFMA acc

#define LSTRIDE 72            // u16 per LDS row: 64 + 8 pad; bank-clean
#define BIMG (128 * LSTRIDE)  // u16 per staged B image (18432 B)

// global -> LDS DMA. LDS dest is wave-uniform base + lane*size.
__device__ __forceinline__ void gl_lds16(const void* g, void* l) {
  __builtin_amdgcn_global_load_lds(
      (const __attribute__((address_space(1))) void*)g,
      (__attribute__((address_space(3))) void*)l, 16, 0, 0);
}
__device__ __forceinline__ void gl_lds4(const void* g, void* l) {
  __builtin_amdgcn_global_load_lds(
      (const __attribute__((address_space(1))) void*)g,
      (__attribute__((address_space(3))) void*)l, 4, 0, 0);
}

// ---------------------------------------------------------------------------
// Precompute: 64 B-panel images (one per (y,kc)) in the EXACT padded LDS
// layout the main kernel stages, fp16-converted once; plus K1*colsum(W).
// Bimg[y*8+kc][(pp*64+o)*72 + kk] = fp16(Wpad[kc*64+kk - 2y - pp][o]),
// pad u16s (kk>=64) zero.  ~1.2 MB in d_ws, L2-resident for the main kernel.
// ---------------------------------------------------------------------------
__global__ __launch_bounds__(256) void byteformer_precompute(
    const float* __restrict__ Wm, u16* __restrict__ Bws,
    float* __restrict__ csumWs) {
  const int t = threadIdx.x;
  const int y = blockIdx.x >> 3, kc = blockIdx.x & 7;
  const int wave = t >> 6, o = t & 63;
  const int pp = wave >> 1, hf = wave & 1;
  u16* img = Bws + (size_t)blockIdx.x * BIMG;
  #pragma unroll
  for (int i = 0; i < 18; ++i) {
    const int kk = (hf * 18 + i) * 2;  // u16 index in row, even, 0..70
    u32 val = 0u;
    if (kk < 64) {
      const int c0 = kc * 64 + kk - 2 * y - pp;
      const int c1 = c0 + 1;
      float f0 = (c0 >= 0 && c0 < 496) ? Wm[c0 * 64 + o] : 0.0f;
      float f1 = (c1 >= 0 && c1 < 496) ? Wm[c1 * 64 + o] : 0.0f;
      u16 h0 = __builtin_bit_cast(unsigned short, (_Float16)f0);
      u16 h1 = __builtin_bit_cast(unsigned short, (_Float16)f1);
      val = (u32)h0 | ((u32)h1 << 16);
    }
    *(u32*)&img[(pp * 64 + o) * LSTRIDE + kk] = val;
  }
  if (blockIdx.x == 0) {  // csum[o] = K1 * sum_c W[c][o]
    __shared__ float red[256];
    float s = 0.0f;
    for (int c = wave * 124; c < wave * 124 + 124; ++c) s += Wm[c * 64 + o];
    red[t] = s;
    __syncthreads();
    if (t < 64)
      csumWs[t] = (1024.0f * (2.0f / 255.0f) + 1.0f) *
                  (red[t] + red[t + 64] + red[t + 128] + red[t + 192]);
  }
}

// ---------------------------------------------------------------------------
// Fused main: out[sub][p*8+q][o] = S*acc - csumWs[o],  S = 2/255
//   acc = sum_m fp16(1024 + w[q][m]) * Bimg[...]
// BM=128 (16 subs x 8 q), BN=128, BK=64. 4 waves 2x2, 64x64 each.
// Per kc: issue B DMA -> A-stage VALU (hides DMA latency) -> barrier ->
// prefetch next x chunk -> ds_read + MFMA.
// ---------------------------------------------------------------------------
__global__ __launch_bounds__(256, 4) void byteformer_fused(
    const int* __restrict__ x, const u16* __restrict__ Bws,
    const float* __restrict__ csumWs, float* __restrict__ out) {
  __shared__ __align__(16) u16 As[128 * LSTRIDE];
  __shared__ __align__(16) u16 Bs[128 * LSTRIDE];

  const int t = threadIdx.x;
  const int mtile = blockIdx.x;        // 0..127 (16 sub-blocks each)
  const int n0 = blockIdx.y * 128;     // 8 n-tiles

  const int wave = t >> 6, lane = t & 63;
  const int wm = wave >> 1, wn = wave & 1;
  const int quad = lane >> 4, l16 = lane & 15;

  // A staging: thread -> (sub, k-group, q-half)
  const int sA_sub = t >> 4;           // 0..15
  const int sA_kg  = (t >> 1) & 7;     // 0..7
  const int sA_qh  = t & 1;            // 0..1
  const long xrow = ((long)mtile * 16 + sA_sub) * 512;

  const char* bimg0 = (const char*)(Bws + (size_t)blockIdx.y * 8 * BIMG);

  floatx4 acc[4][4];
  #pragma unroll
  for (int mt = 0; mt < 4; ++mt)
    #pragma unroll
    for (int nt = 0; nt < 4; ++nt)
      acc[mt][nt] = floatx4{0.f, 0.f, 0.f, 0.f};

  // preload x bytes for kc=0 (9 ints per thread)
  int4 ca, cb; int cc;
  {
    const int base = sA_kg * 8;
    ca = *(const int4*)&x[xrow + base];
    cb = *(const int4*)&x[xrow + base + 4];
    cc = x[xrow + base + 8];
  }

  for (int kc = 0; kc < 8; ++kc) {
    __syncthreads();                   // prev chunk's LDS reads done

    // ---- B stage: pure DMA (18432 B), issued first; L2 latency hides
    // under the A-stage VALU below; drained by the next barrier's vmcnt(0).
    {
      const char* src = bimg0 + (size_t)kc * (BIMG * 2);
      char* dst = (char*)Bs;
      const int woff = wave * 1024;
      #pragma unroll
      for (int j = 0; j < 4; ++j)
        gl_lds16(src + j * 4096 + woff + lane * 16, dst + j * 4096 + woff);
      const int woff4 = 16384 + wave * 256;
      #pragma unroll
      for (int j = 0; j < 2; ++j)
        gl_lds4(src + woff4 + j * 1024 + lane * 4, dst + woff4 + j * 1024);
    }

    // ---- A stage: bytes -> windows -> fp16(1024+v) via 0x6400|v.
    // P-trick: P = w16[2j] | w16[2j+1]<<16; pair output is
    // ((P>>sh) & 0x00FF00FF) | 0x64006400  (1 shift + 1 v_and_or_b32).
    {
      const u32 c0 = (u32)ca.x, c1 = (u32)ca.y, c2 = (u32)ca.z, c3 = (u32)ca.w;
      const u32 c4 = (u32)cb.x, c5 = (u32)cb.y, c6 = (u32)cb.z, c7 = (u32)cb.w;
      const u32 c8 = (u32)cc;
      const u32 P0 = ((c0 << 8) | c1) | (((c1 << 8) | c2) << 16);
      const u32 P1 = ((c2 << 8) | c3) | (((c3 << 8) | c4) << 16);
      const u32 P2 = ((c4 << 8) | c5) | (((c5 << 8) | c6) << 16);
      const u32 P3 = ((c6 << 8) | c7) | (((c7 << 8) | c8) << 16);
      u16* arow = &As[(sA_sub * 8 + sA_qh * 4) * LSTRIDE + sA_kg * 8];
      #pragma unroll
      for (int qi = 0; qi < 4; ++qi) {
        const int sh = 8 - (sA_qh * 4 + qi);
        int4 d;
        d.x = (int)(((P0 >> sh) & 0x00FF00FFu) | 0x64006400u);
        d.y = (int)(((P1 >> sh) & 0x00FF00FFu) | 0x64006400u);
        d.z = (int)(((P2 >> sh) & 0x00FF00FFu) | 0x64006400u);
        d.w = (int)(((P3 >> sh) & 0x00FF00FFu) | 0x64006400u);
        *(int4*)(arow + qi * LSTRIDE) = d;   // rows 16B-aligned (144B pitch)
      }
    }

    __syncthreads();                   // A written, B DMA landed

    // ---- x prefetch for kc+1: latency hides under the MFMA phase; the
    // vmcnt(0) drain lands at the NEXT iteration's first barrier.
    if (kc < 7) {
      const int base = (kc + 1) * 64 + sA_kg * 8;
      ca = *(const int4*)&x[xrow + base];
      cb = *(const int4*)&x[xrow + base + 4];
      cc = (base + 8 < 512) ? x[xrow + base + 8] : 0;
    }

    // ---- compute: 2 k-steps of 32, aligned ds_read_b128 fragments
    #pragma unroll
    for (int ks = 0; ks < 2; ++ks) {
      const int koff = ks * 32 + quad * 8;
      half8 af[4], bf[4];
      #pragma unroll
      for (int mt = 0; mt < 4; ++mt)
        af[mt] = *(const half8*)&As[(wm * 64 + mt * 16 + l16) * LSTRIDE + koff];
      #pragma unroll
      for (int nt = 0; nt < 4; ++nt)
        bf[nt] = *(const half8*)&Bs[(wn * 64 + nt * 16 + l16) * LSTRIDE + koff];
      #pragma unroll
      for (int mt = 0; mt < 4; ++mt)
        #pragma unroll
        for (int nt = 0; nt < 4; ++nt)
          acc[mt][nt] = __builtin_amdgcn_mfma_f32_16x16x32_f16(
              af[mt], bf[nt], acc[mt][nt], 0, 0, 0);
    }
  }

  // ---- epilogue: C/D layout col=l16, row=quad*4+reg (verified)
  const float S = 2.0f / 255.0f;
  #pragma unroll
  for (int nt = 0; nt < 4; ++nt) {
    int n = n0 + wn * 64 + nt * 16 + l16;
    int p = n >> 6, o = n & 63;
    float cs = csumWs[o];              // K1 pre-baked in precompute
    #pragma unroll
    for (int mt = 0; mt < 4; ++mt) {
      int mbase = mtile * 128 + wm * 64 + mt * 16 + quad * 4;
      #pragma unroll
      for (int i = 0; i < 4; ++i) {
        int mr = mbase + i;
        int sub = mr >> 3, q = mr & 7;
        out[(long)sub * 8192 + (p * 8 + q) * 64 + o] = S * acc[mt][nt][i] - cs;
      }
    }
  }
}

extern "C" void kernel_launch(void* const* d_in, const int* in_sizes, int n_in,
                              void* d_out, int out_size, void* d_ws, size_t ws_size,
                              hipStream_t stream) {
  const int* x = (const int*)d_in[0];        // (256, 4096) byte values as int32
  const float* Wm = (const float*)d_in[1];   // (496, 64) fp32
  float* out = (float*)d_out;                // (256, 8, 128, 64) fp32
  u16* Bws = (u16*)d_ws;                                    // 1,179,648 B
  float* csumWs = (float*)((char*)d_ws + (size_t)64 * BIMG * 2);  // +256 B
  byteformer_precompute<<<dim3(64), dim3(256), 0, stream>>>(Wm, Bws, csumWs);
  byteformer_fused<<<dim3(128, 8), dim3(256), 0, stream>>>(x, Bws, csumWs, out);
}